// Round 3
// baseline (729.071 us; speedup 1.0000x reference)
//
#include <hip/hip_runtime.h>
#include <hip/hip_bf16.h>
#include <stdint.h>
#include <stddef.h>

// ---------- types ----------
typedef __attribute__((ext_vector_type(8))) short bf16x8;          // 8 bf16 in 4 VGPRs
typedef __attribute__((ext_vector_type(8))) unsigned short u16x8;  // 16B vector
typedef __attribute__((ext_vector_type(4))) float f32x4;

#define MFMA16(a, b, c) __builtin_amdgcn_mfma_f32_16x16x32_bf16((a), (b), (c), 0, 0, 0)

__device__ __forceinline__ unsigned short f2b(float f) {  // f32 -> bf16 RNE
  union { float f; unsigned u; } v; v.f = f;
  unsigned r = v.u + 0x7fffu + ((v.u >> 16) & 1u);
  return (unsigned short)(r >> 16);
}
__device__ __forceinline__ float b2f(unsigned short h) {
  union { unsigned u; float f; } v; v.u = ((unsigned)h) << 16;
  return v.f;
}

__device__ __forceinline__ void gload_lds16(const void* g, void* l) {
  __builtin_amdgcn_global_load_lds((const __attribute__((address_space(1))) void*)g,
                                   (__attribute__((address_space(3))) void*)l, 16, 0, 0);
}

// ---------- transpose + convert f32 (K x N) -> bf16 (N x K) ----------
__global__ void k_transpose_f32_bf16(const float* __restrict__ in,
                                     unsigned short* __restrict__ out,
                                     int K, int N) {
  __shared__ float tile[64][65];
  const int kb = blockIdx.x * 64;
  const int nb = blockIdx.y * 64;
  const int t = threadIdx.x;          // 256
  const int c4 = (t & 15) * 4;
  const int rr = t >> 4;              // 0..15
#pragma unroll
  for (int i = 0; i < 4; ++i) {
    int r = rr + i * 16;
    float4 v = *reinterpret_cast<const float4*>(in + (size_t)(kb + r) * N + nb + c4);
    tile[r][c4 + 0] = v.x; tile[r][c4 + 1] = v.y;
    tile[r][c4 + 2] = v.z; tile[r][c4 + 3] = v.w;
  }
  __syncthreads();
#pragma unroll
  for (int i = 0; i < 4; ++i) {
    int n = rr + i * 16;
    ushort4 w;
    w.x = f2b(tile[c4 + 0][n]); w.y = f2b(tile[c4 + 1][n]);
    w.z = f2b(tile[c4 + 2][n]); w.w = f2b(tile[c4 + 3][n]);
    *reinterpret_cast<ushort4*>(out + (size_t)(nb + n) * K + kb + c4) = w;
  }
}

// ---------- elementwise f32 -> bf16 ----------
__global__ void k_f32_to_bf16(const float* __restrict__ in, unsigned short* __restrict__ out) {
  size_t i = ((size_t)blockIdx.x * blockDim.x + threadIdx.x) * 4;
  float4 v = *reinterpret_cast<const float4*>(in + i);
  ushort4 w; w.x = f2b(v.x); w.y = f2b(v.y); w.z = f2b(v.z); w.w = f2b(v.w);
  *reinterpret_cast<ushort4*>(out + i) = w;
}

// ---------- GEMM: C[M,N] = A[M,K] (bf16, row-major) * Bt[N,K]^T (bf16, K-major) ----------
template <bool OUT_F32>
__global__ void __launch_bounds__(256, 2)
k_gemm(const unsigned short* __restrict__ A, const unsigned short* __restrict__ Bt,
       void* __restrict__ C, int M, int N, int K) {
  __shared__ unsigned short As[128 * 32];
  __shared__ unsigned short Bs[128 * 32];
  const int m0 = blockIdx.x * 128;
  const int n0 = blockIdx.y * 128;
  const int tid = threadIdx.x;
  const int lane = tid & 63;
  const int w = tid >> 6;
  const int wr = w >> 1, wc = w & 1;
  const int cl = lane & 15, rg = lane >> 4;
  const int ko = rg * 8;

  f32x4 acc[4][4] = {};

  for (int k0 = 0; k0 < K; k0 += 32) {
#pragma unroll
    for (int i = 0; i < 2; ++i) {
      int c = i * 256 + tid;
      gload_lds16(A + (size_t)(m0 + (c >> 2)) * K + k0 + (c & 3) * 8, As + c * 8);
    }
#pragma unroll
    for (int i = 0; i < 2; ++i) {
      int c = i * 256 + tid;
      gload_lds16(Bt + (size_t)(n0 + (c >> 2)) * K + k0 + (c & 3) * 8, Bs + c * 8);
    }
    __syncthreads();
    bf16x8 a[4], b[4];
#pragma unroll
    for (int mi = 0; mi < 4; ++mi)
      a[mi] = *reinterpret_cast<const bf16x8*>(As + (wr * 64 + mi * 16 + cl) * 32 + ko);
#pragma unroll
    for (int ni = 0; ni < 4; ++ni)
      b[ni] = *reinterpret_cast<const bf16x8*>(Bs + (wc * 64 + ni * 16 + cl) * 32 + ko);
#pragma unroll
    for (int mi = 0; mi < 4; ++mi)
#pragma unroll
      for (int ni = 0; ni < 4; ++ni)
        acc[mi][ni] = MFMA16(a[mi], b[ni], acc[mi][ni]);
    __syncthreads();
  }
#pragma unroll
  for (int mi = 0; mi < 4; ++mi)
#pragma unroll
    for (int ni = 0; ni < 4; ++ni) {
      int row = m0 + wr * 64 + mi * 16 + rg * 4;
      int col = n0 + wc * 64 + ni * 16 + cl;
#pragma unroll
      for (int r = 0; r < 4; ++r) {
        float v = acc[mi][ni][r];
        if (OUT_F32) ((float*)C)[(size_t)(row + r) * N + col] = v;
        else         ((unsigned short*)C)[(size_t)(row + r) * N + col] = f2b(v);
      }
    }
}

// ---------- RoPE + reshape: Cpre[S,6144] -> Qr[H,S,DH] (pre-scaled), Kr[KV,S,DH] ----------
__global__ void k_rope(const unsigned short* __restrict__ Cpre,
                       const float* __restrict__ cosb, const float* __restrict__ sinb,
                       unsigned short* __restrict__ Qr, unsigned short* __restrict__ Kr) {
  const int s = blockIdx.x;
  const int hh = blockIdx.y;      // 0-31 q heads, 32-39 k heads
  const int d = threadIdx.x;      // 0..127
  const int col = (hh < 32) ? hh * 128 + d : 4096 + (hh - 32) * 128 + d;
  float t = b2f(Cpre[(size_t)s * 6144 + col]);
  const int dp = (d < 64) ? d + 64 : d - 64;
  float tp = b2f(Cpre[(size_t)s * 6144 + (col - d + dp)]);
  float rot = (d < 64) ? -tp : tp;
  float o = t * cosb[s * 128 + d] + rot * sinb[s * 128 + d];
  if (hh < 32) {
    // fold attention scale 1/sqrt(128) into Q
    Qr[((size_t)hh * 2048 + s) * 128 + d] = f2b(o * 0.08838834764831845f);
  } else {
    Kr[((size_t)(hh - 32) * 2048 + s) * 128 + d] = f2b(o);
  }
}

// ---------- V transpose: Cpre[S, 5120 + kv*128 + d] -> Vt[KV, DH, S] ----------
__global__ void k_transpose_v(const unsigned short* __restrict__ Cpre,
                              unsigned short* __restrict__ Vt) {
  __shared__ unsigned short tile[64][72];
  const int sb = blockIdx.x * 64;
  const int db = blockIdx.y * 64;
  const int kv = blockIdx.z;
  const int t = threadIdx.x;
#pragma unroll
  for (int i = 0; i < 2; ++i) {
    int sl = i * 32 + (t >> 3);
    int d8 = (t & 7) * 8;
    const unsigned short* src = Cpre + (size_t)(sb + sl) * 6144 + 5120 + kv * 128 + db + d8;
    ushort4 v0 = *reinterpret_cast<const ushort4*>(src);
    ushort4 v1 = *reinterpret_cast<const ushort4*>(src + 4);
    *reinterpret_cast<ushort4*>(&tile[sl][d8]) = v0;
    *reinterpret_cast<ushort4*>(&tile[sl][d8 + 4]) = v1;
  }
  __syncthreads();
#pragma unroll
  for (int i = 0; i < 2; ++i) {
    int dl = i * 32 + (t >> 3);
    int s8 = (t & 7) * 8;
    ushort4 w0, w1;
    w0.x = tile[s8 + 0][dl]; w0.y = tile[s8 + 1][dl]; w0.z = tile[s8 + 2][dl]; w0.w = tile[s8 + 3][dl];
    w1.x = tile[s8 + 4][dl]; w1.y = tile[s8 + 5][dl]; w1.z = tile[s8 + 6][dl]; w1.w = tile[s8 + 7][dl];
    unsigned short* dst = Vt + ((size_t)kv * 128 + db + dl) * 2048 + sb + s8;
    *reinterpret_cast<ushort4*>(dst) = w0;
    *reinterpret_cast<ushort4*>(dst + 4) = w1;
  }
}

// ---------- fused causal GQA flash attention (v3) ----------
// QBLK=64: 1024 blocks (4/CU), LDS 40KB (4 blocks/CU), VGPR<=128 (4 waves/SIMD).
// Each of 4 waves owns 16 q-rows. Reg-staged K/V prefetch across compute phase;
// raw s_barrier (no vmcnt drain); P wave-private (no barrier before PV).
#define QBLK 64
#define KVBLK 64
__global__ void __launch_bounds__(256, 4)
k_attn(const unsigned short* __restrict__ Qr, const unsigned short* __restrict__ Kr,
       const unsigned short* __restrict__ Vt, unsigned short* __restrict__ ctx) {
  __shared__ unsigned short Ks[64 * 128];   // [kv_local][d]  swizzled, 16KB
  __shared__ unsigned short Vs[128 * 64];   // [d][kv_local]  swizzled, 16KB
  __shared__ unsigned short Ps[64 * 64];    // [q_local][kv_local] swizzled, 8KB
  const int bid = blockIdx.x;
  const int kv = bid & 7;                   // XCD-aligned kv head
  const int h  = kv * 4 + ((bid >> 3) & 3);
  const int qb = 31 - (bid >> 5);           // heavy-first
  const int q0 = qb * QBLK;
  const int tid = threadIdx.x;
  const int lane = tid & 63;
  const int w = tid >> 6;
  const int cl = lane & 15, rg = lane >> 4;

  const unsigned short* Kbase = Kr + (size_t)kv * 2048 * 128;
  const unsigned short* Vbase = Vt + (size_t)kv * 128 * 2048;

  // Q fragments: rows q0 + w*16 + cl, k = kk*32 + rg*8  (Q pre-scaled by 1/sqrt(d))
  bf16x8 qf[4];
#pragma unroll
  for (int kk = 0; kk < 4; ++kk)
    qf[kk] = *reinterpret_cast<const bf16x8*>(
        Qr + ((size_t)h * 2048 + q0 + w * 16 + cl) * 128 + kk * 32 + rg * 8);

  f32x4 po[8] = {};
  float mrow[4], lrow[4];
#pragma unroll
  for (int r = 0; r < 4; ++r) { mrow[r] = -1e30f; lrow[r] = 0.f; }

  // staging geometry
  const int krr = tid >> 4;             // 0..15
  const int kcc = (tid & 15) * 8;
  const int vrr = tid >> 3;             // 0..31
  const int vcc = (tid & 7) * 8;

  // prologue: prefetch tile 0 into registers
  u16x8 kst[4], vst[4];
#pragma unroll
  for (int i = 0; i < 4; ++i)
    kst[i] = *reinterpret_cast<const u16x8*>(Kbase + (size_t)(i * 16 + krr) * 128 + kcc);
#pragma unroll
  for (int i = 0; i < 4; ++i)
    vst[i] = *reinterpret_cast<const u16x8*>(Vbase + (size_t)(i * 32 + vrr) * 2048 + vcc);

  const int jmax = qb + 1;
  for (int j = 0; j < jmax; ++j) {
    // barrier A: all waves done reading previous tile's LDS
    asm volatile("" ::: "memory");
    __builtin_amdgcn_s_barrier();
    asm volatile("" ::: "memory");
    // staged regs -> LDS (swizzled)
#pragma unroll
    for (int i = 0; i < 4; ++i) {
      int row = i * 16 + krr;
      int off = (row * 256 + kcc * 2) ^ ((row & 7) << 4);
      *reinterpret_cast<u16x8*>((char*)Ks + off) = kst[i];
    }
#pragma unroll
    for (int i = 0; i < 4; ++i) {
      int row = i * 32 + vrr;
      int off = (row * 128 + vcc * 2) ^ ((row & 7) << 4);
      *reinterpret_cast<u16x8*>((char*)Vs + off) = vst[i];
    }
    // issue prefetch for next tile (stays in flight across compute)
    const int jn = (j + 1 < jmax) ? j + 1 : j;
#pragma unroll
    for (int i = 0; i < 4; ++i)
      kst[i] = *reinterpret_cast<const u16x8*>(
          Kbase + (size_t)(jn * 64 + i * 16 + krr) * 128 + kcc);
#pragma unroll
    for (int i = 0; i < 4; ++i)
      vst[i] = *reinterpret_cast<const u16x8*>(
          Vbase + (size_t)(i * 32 + vrr) * 2048 + jn * 64 + vcc);
    // barrier B: LDS writes visible; vmcnt NOT drained
    asm volatile("s_waitcnt lgkmcnt(0)" ::: "memory");
    __builtin_amdgcn_s_barrier();
    asm volatile("" ::: "memory");

    // S = Q K^T : rows = 16 q of this wave, cols = 64 kv
    f32x4 sa[4] = {};
    __builtin_amdgcn_s_setprio(1);
#pragma unroll
    for (int ni = 0; ni < 4; ++ni)
#pragma unroll
      for (int kk = 0; kk < 4; ++kk) {
        int row = ni * 16 + cl;
        int off = (row * 256 + (kk * 32 + rg * 8) * 2) ^ ((row & 7) << 4);
        bf16x8 bfr = *reinterpret_cast<const bf16x8*>((const char*)Ks + off);
        sa[ni] = MFMA16(qf[kk], bfr, sa[ni]);
      }
    __builtin_amdgcn_s_setprio(0);

    // causal mask: only the diagonal tile (j == jmax-1) has masked entries
    if (j == jmax - 1) {
      int qbase = w * 16 + rg * 4;  // within-tile q (tile q offset == tile k offset)
#pragma unroll
      for (int ni = 0; ni < 4; ++ni) {
        int kcol = ni * 16 + cl;
#pragma unroll
        for (int r = 0; r < 4; ++r)
          if (kcol > qbase + r) sa[ni][r] = -1e30f;
      }
    }

    // online softmax (row lives in the 16 lanes sharing rg)
#pragma unroll
    for (int r = 0; r < 4; ++r) {
      float t = fmaxf(fmaxf(sa[0][r], sa[1][r]), fmaxf(sa[2][r], sa[3][r]));
      t = fmaxf(t, __shfl_xor(t, 1));
      t = fmaxf(t, __shfl_xor(t, 2));
      t = fmaxf(t, __shfl_xor(t, 4));
      t = fmaxf(t, __shfl_xor(t, 8));
      float mnew = fmaxf(mrow[r], t);
      float sf = __expf(mrow[r] - mnew);
      mrow[r] = mnew;
#pragma unroll
      for (int di = 0; di < 8; ++di) po[di][r] *= sf;
      float rs = 0.f;
#pragma unroll
      for (int ni = 0; ni < 4; ++ni) {
        float p = __expf(sa[ni][r] - mnew);
        sa[ni][r] = p;
        rs += p;
      }
      rs += __shfl_xor(rs, 1);
      rs += __shfl_xor(rs, 2);
      rs += __shfl_xor(rs, 4);
      rs += __shfl_xor(rs, 8);
      lrow[r] = lrow[r] * sf + rs;
    }

    // write P (wave-private 16-row slab; in-wave LDS ordering only)
#pragma unroll
    for (int ni = 0; ni < 4; ++ni)
#pragma unroll
      for (int r = 0; r < 4; ++r) {
        int prow = w * 16 + rg * 4 + r;
        int off = (prow * 128 + (ni * 16 + cl) * 2) ^ ((prow & 7) << 4);
        *(unsigned short*)((char*)Ps + off) = f2b(sa[ni][r]);
      }
    asm volatile("s_waitcnt lgkmcnt(0)" ::: "memory");
    __builtin_amdgcn_sched_barrier(0);

    // O += P V
    __builtin_amdgcn_s_setprio(1);
#pragma unroll
    for (int kk = 0; kk < 2; ++kk) {
      int prow = w * 16 + cl;
      int poff = (prow * 128 + (kk * 32 + rg * 8) * 2) ^ ((prow & 7) << 4);
      bf16x8 pa = *reinterpret_cast<const bf16x8*>((const char*)Ps + poff);
#pragma unroll
      for (int di = 0; di < 8; ++di) {
        int vrow = di * 16 + cl;
        int voff = (vrow * 128 + (kk * 32 + rg * 8) * 2) ^ ((vrow & 7) << 4);
        bf16x8 vb = *reinterpret_cast<const bf16x8*>((const char*)Vs + voff);
        po[di] = MFMA16(pa, vb, po[di]);
      }
    }
    __builtin_amdgcn_s_setprio(0);
  }

  // epilogue: normalize, write ctx[s][h*128+d]
#pragma unroll
  for (int r = 0; r < 4; ++r) {
    float inv = 1.0f / lrow[r];
    int srow = q0 + w * 16 + rg * 4 + r;
#pragma unroll
    for (int di = 0; di < 8; ++di)
      ctx[(size_t)srow * 4096 + h * 128 + di * 16 + cl] = f2b(po[di][r] * inv);
  }
}

// ---------- launch ----------
extern "C" void kernel_launch(void* const* d_in, const int* in_sizes, int n_in,
                              void* d_out, int out_size, void* d_ws, size_t ws_size,
                              hipStream_t stream) {
  const float* X    = (const float*)d_in[0];
  const float* cosb = (const float*)d_in[2];
  const float* sinb = (const float*)d_in[3];
  const float* Wq   = (const float*)d_in[4];
  const float* Wk   = (const float*)d_in[5];
  const float* Wv   = (const float*)d_in[6];
  const float* Wo   = (const float*)d_in[7];

  char* ws = (char*)d_ws;
  unsigned short* WT   = (unsigned short*)(ws + 0);           // 6144x4096 bf16 (later: WoT)
  unsigned short* Xb   = (unsigned short*)(ws + 50331648ull); // 2048x4096 bf16
  unsigned short* Cpre = (unsigned short*)(ws + 67108864ull); // 2048x6144 bf16 (later: ctx)
  unsigned short* Qr   = (unsigned short*)(ws + 92274688ull); // 32x2048x128 bf16
  unsigned short* Kr   = (unsigned short*)(ws + 109051904ull);// 8x2048x128 bf16
  unsigned short* Vt   = (unsigned short*)(ws + 113246208ull);// 8x128x2048 bf16
  unsigned short* ctx  = Cpre;

  k_transpose_f32_bf16<<<dim3(64, 64), 256, 0, stream>>>(Wq, WT, 4096, 4096);
  k_transpose_f32_bf16<<<dim3(64, 16), 256, 0, stream>>>(Wk, WT + (size_t)4096 * 4096, 4096, 1024);
  k_transpose_f32_bf16<<<dim3(64, 16), 256, 0, stream>>>(Wv, WT + (size_t)5120 * 4096, 4096, 1024);
  k_f32_to_bf16<<<8192, 256, 0, stream>>>(X, Xb);

  k_gemm<false><<<dim3(16, 48), 256, 0, stream>>>(Xb, WT, Cpre, 2048, 6144, 4096);

  k_rope<<<dim3(2048, 40), 128, 0, stream>>>(Cpre, cosb, sinb, Qr, Kr);
  k_transpose_v<<<dim3(32, 2, 8), 256, 0, stream>>>(Cpre, Vt);

  k_transpose_f32_bf16<<<dim3(64, 64), 256, 0, stream>>>(Wo, WT, 4096, 4096);

  k_attn<<<1024, 256, 0, stream>>>(Qr, Kr, Vt, ctx);

  k_gemm<true><<<dim3(16, 32), 256, 0, stream>>>(ctx, WT, d_out, 2048, 4096, 4096);
}

// Round 4
// 444.076 us; speedup vs baseline: 1.6418x; 1.6418x over previous
//
#include <hip/hip_runtime.h>
#include <hip/hip_bf16.h>
#include <stdint.h>
#include <stddef.h>

// ---------- types ----------
typedef __attribute__((ext_vector_type(8))) short bf16x8;          // 8 bf16 in 4 VGPRs
typedef __attribute__((ext_vector_type(8))) unsigned short u16x8;  // 16B vector
typedef __attribute__((ext_vector_type(4))) float f32x4;

#define MFMA16(a, b, c) __builtin_amdgcn_mfma_f32_16x16x32_bf16((a), (b), (c), 0, 0, 0)

__device__ __forceinline__ unsigned short f2b(float f) {  // f32 -> bf16 RNE
  union { float f; unsigned u; } v; v.f = f;
  unsigned r = v.u + 0x7fffu + ((v.u >> 16) & 1u);
  return (unsigned short)(r >> 16);
}
__device__ __forceinline__ float b2f(unsigned short h) {
  union { unsigned u; float f; } v; v.u = ((unsigned)h) << 16;
  return v.f;
}

__device__ __forceinline__ void gload_lds16(const void* g, void* l) {
  __builtin_amdgcn_global_load_lds((const __attribute__((address_space(1))) void*)g,
                                   (__attribute__((address_space(3))) void*)l, 16, 0, 0);
}

// ---------- transpose + convert f32 (K x N) -> bf16 (N x K) ----------
__global__ void k_transpose_f32_bf16(const float* __restrict__ in,
                                     unsigned short* __restrict__ out,
                                     int K, int N) {
  __shared__ float tile[64][65];
  const int kb = blockIdx.x * 64;
  const int nb = blockIdx.y * 64;
  const int t = threadIdx.x;          // 256
  const int c4 = (t & 15) * 4;
  const int rr = t >> 4;              // 0..15
#pragma unroll
  for (int i = 0; i < 4; ++i) {
    int r = rr + i * 16;
    float4 v = *reinterpret_cast<const float4*>(in + (size_t)(kb + r) * N + nb + c4);
    tile[r][c4 + 0] = v.x; tile[r][c4 + 1] = v.y;
    tile[r][c4 + 2] = v.z; tile[r][c4 + 3] = v.w;
  }
  __syncthreads();
#pragma unroll
  for (int i = 0; i < 4; ++i) {
    int n = rr + i * 16;
    ushort4 w;
    w.x = f2b(tile[c4 + 0][n]); w.y = f2b(tile[c4 + 1][n]);
    w.z = f2b(tile[c4 + 2][n]); w.w = f2b(tile[c4 + 3][n]);
    *reinterpret_cast<ushort4*>(out + (size_t)(nb + n) * K + kb + c4) = w;
  }
}

// ---------- elementwise f32 -> bf16 ----------
__global__ void k_f32_to_bf16(const float* __restrict__ in, unsigned short* __restrict__ out) {
  size_t i = ((size_t)blockIdx.x * blockDim.x + threadIdx.x) * 4;
  float4 v = *reinterpret_cast<const float4*>(in + i);
  ushort4 w; w.x = f2b(v.x); w.y = f2b(v.y); w.z = f2b(v.z); w.w = f2b(v.w);
  *reinterpret_cast<ushort4*>(out + i) = w;
}

// ---------- GEMM: C[M,N] = A[M,K] (bf16, row-major) * Bt[N,K]^T (bf16, K-major) ----------
template <bool OUT_F32>
__global__ void __launch_bounds__(256, 2)
k_gemm(const unsigned short* __restrict__ A, const unsigned short* __restrict__ Bt,
       void* __restrict__ C, int M, int N, int K) {
  __shared__ unsigned short As[128 * 32];
  __shared__ unsigned short Bs[128 * 32];
  const int m0 = blockIdx.x * 128;
  const int n0 = blockIdx.y * 128;
  const int tid = threadIdx.x;
  const int lane = tid & 63;
  const int w = tid >> 6;
  const int wr = w >> 1, wc = w & 1;
  const int cl = lane & 15, rg = lane >> 4;
  const int ko = rg * 8;

  f32x4 acc[4][4] = {};

  for (int k0 = 0; k0 < K; k0 += 32) {
#pragma unroll
    for (int i = 0; i < 2; ++i) {
      int c = i * 256 + tid;
      gload_lds16(A + (size_t)(m0 + (c >> 2)) * K + k0 + (c & 3) * 8, As + c * 8);
    }
#pragma unroll
    for (int i = 0; i < 2; ++i) {
      int c = i * 256 + tid;
      gload_lds16(Bt + (size_t)(n0 + (c >> 2)) * K + k0 + (c & 3) * 8, Bs + c * 8);
    }
    __syncthreads();
    bf16x8 a[4], b[4];
#pragma unroll
    for (int mi = 0; mi < 4; ++mi)
      a[mi] = *reinterpret_cast<const bf16x8*>(As + (wr * 64 + mi * 16 + cl) * 32 + ko);
#pragma unroll
    for (int ni = 0; ni < 4; ++ni)
      b[ni] = *reinterpret_cast<const bf16x8*>(Bs + (wc * 64 + ni * 16 + cl) * 32 + ko);
#pragma unroll
    for (int mi = 0; mi < 4; ++mi)
#pragma unroll
      for (int ni = 0; ni < 4; ++ni)
        acc[mi][ni] = MFMA16(a[mi], b[ni], acc[mi][ni]);
    __syncthreads();
  }
#pragma unroll
  for (int mi = 0; mi < 4; ++mi)
#pragma unroll
    for (int ni = 0; ni < 4; ++ni) {
      int row = m0 + wr * 64 + mi * 16 + rg * 4;
      int col = n0 + wc * 64 + ni * 16 + cl;
#pragma unroll
      for (int r = 0; r < 4; ++r) {
        float v = acc[mi][ni][r];
        if (OUT_F32) ((float*)C)[(size_t)(row + r) * N + col] = v;
        else         ((unsigned short*)C)[(size_t)(row + r) * N + col] = f2b(v);
      }
    }
}

// ---------- RoPE + reshape: Cpre[S,6144] -> Qr[H,S,DH] (pre-scaled), Kr[KV,S,DH] ----------
__global__ void k_rope(const unsigned short* __restrict__ Cpre,
                       const float* __restrict__ cosb, const float* __restrict__ sinb,
                       unsigned short* __restrict__ Qr, unsigned short* __restrict__ Kr) {
  const int s = blockIdx.x;
  const int hh = blockIdx.y;      // 0-31 q heads, 32-39 k heads
  const int d = threadIdx.x;      // 0..127
  const int col = (hh < 32) ? hh * 128 + d : 4096 + (hh - 32) * 128 + d;
  float t = b2f(Cpre[(size_t)s * 6144 + col]);
  const int dp = (d < 64) ? d + 64 : d - 64;
  float tp = b2f(Cpre[(size_t)s * 6144 + (col - d + dp)]);
  float rot = (d < 64) ? -tp : tp;
  float o = t * cosb[s * 128 + d] + rot * sinb[s * 128 + d];
  if (hh < 32) {
    Qr[((size_t)hh * 2048 + s) * 128 + d] = f2b(o * 0.08838834764831845f);
  } else {
    Kr[((size_t)(hh - 32) * 2048 + s) * 128 + d] = f2b(o);
  }
}

// ---------- V transpose: Cpre[S, 5120 + kv*128 + d] -> Vt[KV, DH, S] ----------
__global__ void k_transpose_v(const unsigned short* __restrict__ Cpre,
                              unsigned short* __restrict__ Vt) {
  __shared__ unsigned short tile[64][72];
  const int sb = blockIdx.x * 64;
  const int db = blockIdx.y * 64;
  const int kv = blockIdx.z;
  const int t = threadIdx.x;
#pragma unroll
  for (int i = 0; i < 2; ++i) {
    int sl = i * 32 + (t >> 3);
    int d8 = (t & 7) * 8;
    const unsigned short* src = Cpre + (size_t)(sb + sl) * 6144 + 5120 + kv * 128 + db + d8;
    ushort4 v0 = *reinterpret_cast<const ushort4*>(src);
    ushort4 v1 = *reinterpret_cast<const ushort4*>(src + 4);
    *reinterpret_cast<ushort4*>(&tile[sl][d8]) = v0;
    *reinterpret_cast<ushort4*>(&tile[sl][d8 + 4]) = v1;
  }
  __syncthreads();
#pragma unroll
  for (int i = 0; i < 2; ++i) {
    int dl = i * 32 + (t >> 3);
    int s8 = (t & 7) * 8;
    ushort4 w0, w1;
    w0.x = tile[s8 + 0][dl]; w0.y = tile[s8 + 1][dl]; w0.z = tile[s8 + 2][dl]; w0.w = tile[s8 + 3][dl];
    w1.x = tile[s8 + 4][dl]; w1.y = tile[s8 + 5][dl]; w1.z = tile[s8 + 6][dl]; w1.w = tile[s8 + 7][dl];
    unsigned short* dst = Vt + ((size_t)kv * 128 + db + dl) * 2048 + sb + s8;
    *reinterpret_cast<ushort4*>(dst) = w0;
    *reinterpret_cast<ushort4*>(dst + 4) = w1;
  }
}

// ---------- fused causal GQA flash attention (v4) ----------
// QBLK=64: 1024 blocks; LDS 40KB. __launch_bounds__(256,3): VGPR cap ~168 ->
// no spill (R3's (256,4) cap=128 spilled to scratch: 584MB HBM/dispatch).
// 3 blocks/CU (VGPR-limited), 12 waves/CU.
#define QBLK 64
#define KVBLK 64
__global__ void __launch_bounds__(256, 3)
k_attn(const unsigned short* __restrict__ Qr, const unsigned short* __restrict__ Kr,
       const unsigned short* __restrict__ Vt, unsigned short* __restrict__ ctx) {
  __shared__ unsigned short Ks[64 * 128];   // [kv_local][d]  swizzled, 16KB
  __shared__ unsigned short Vs[128 * 64];   // [d][kv_local]  swizzled, 16KB
  __shared__ unsigned short Ps[64 * 64];    // [q_local][kv_local] swizzled, 8KB
  const int bid = blockIdx.x;
  const int kv = bid & 7;                   // XCD-aligned kv head
  const int h  = kv * 4 + ((bid >> 3) & 3);
  const int qb = 31 - (bid >> 5);           // heavy-first
  const int q0 = qb * QBLK;
  const int tid = threadIdx.x;
  const int lane = tid & 63;
  const int w = tid >> 6;
  const int cl = lane & 15, rg = lane >> 4;

  const unsigned short* Kbase = Kr + (size_t)kv * 2048 * 128;
  const unsigned short* Vbase = Vt + (size_t)kv * 128 * 2048;

  // Q fragments: rows q0 + w*16 + cl, k = kk*32 + rg*8  (Q pre-scaled by 1/sqrt(d))
  bf16x8 qf[4];
#pragma unroll
  for (int kk = 0; kk < 4; ++kk)
    qf[kk] = *reinterpret_cast<const bf16x8*>(
        Qr + ((size_t)h * 2048 + q0 + w * 16 + cl) * 128 + kk * 32 + rg * 8);

  f32x4 po[8] = {};
  float mrow[4], lrow[4];
#pragma unroll
  for (int r = 0; r < 4; ++r) { mrow[r] = -1e30f; lrow[r] = 0.f; }

  // staging geometry
  const int krr = tid >> 4;             // 0..15
  const int kcc = (tid & 15) * 8;
  const int vrr = tid >> 3;             // 0..31
  const int vcc = (tid & 7) * 8;

  // prologue: prefetch tile 0 into registers
  u16x8 kst[4], vst[4];
#pragma unroll
  for (int i = 0; i < 4; ++i)
    kst[i] = *reinterpret_cast<const u16x8*>(Kbase + (size_t)(i * 16 + krr) * 128 + kcc);
#pragma unroll
  for (int i = 0; i < 4; ++i)
    vst[i] = *reinterpret_cast<const u16x8*>(Vbase + (size_t)(i * 32 + vrr) * 2048 + vcc);

  const int jmax = qb + 1;
  for (int j = 0; j < jmax; ++j) {
    // barrier A: all waves done reading previous tile's LDS
    asm volatile("" ::: "memory");
    __builtin_amdgcn_s_barrier();
    asm volatile("" ::: "memory");
    // staged regs -> LDS (swizzled)
#pragma unroll
    for (int i = 0; i < 4; ++i) {
      int row = i * 16 + krr;
      int off = (row * 256 + kcc * 2) ^ ((row & 7) << 4);
      *reinterpret_cast<u16x8*>((char*)Ks + off) = kst[i];
    }
#pragma unroll
    for (int i = 0; i < 4; ++i) {
      int row = i * 32 + vrr;
      int off = (row * 128 + vcc * 2) ^ ((row & 7) << 4);
      *reinterpret_cast<u16x8*>((char*)Vs + off) = vst[i];
    }
    // issue prefetch for next tile (stays in flight across compute)
    const int jn = (j + 1 < jmax) ? j + 1 : j;
#pragma unroll
    for (int i = 0; i < 4; ++i)
      kst[i] = *reinterpret_cast<const u16x8*>(
          Kbase + (size_t)(jn * 64 + i * 16 + krr) * 128 + kcc);
#pragma unroll
    for (int i = 0; i < 4; ++i)
      vst[i] = *reinterpret_cast<const u16x8*>(
          Vbase + (size_t)(i * 32 + vrr) * 2048 + jn * 64 + vcc);
    // barrier B: LDS writes visible; vmcnt NOT drained
    asm volatile("s_waitcnt lgkmcnt(0)" ::: "memory");
    __builtin_amdgcn_s_barrier();
    asm volatile("" ::: "memory");

    // S = Q K^T : rows = 16 q of this wave, cols = 64 kv
    f32x4 sa[4] = {};
    __builtin_amdgcn_s_setprio(1);
#pragma unroll
    for (int ni = 0; ni < 4; ++ni)
#pragma unroll
      for (int kk = 0; kk < 4; ++kk) {
        int row = ni * 16 + cl;
        int off = (row * 256 + (kk * 32 + rg * 8) * 2) ^ ((row & 7) << 4);
        bf16x8 bfr = *reinterpret_cast<const bf16x8*>((const char*)Ks + off);
        sa[ni] = MFMA16(qf[kk], bfr, sa[ni]);
      }
    __builtin_amdgcn_s_setprio(0);

    // causal mask: only the diagonal tile (j == jmax-1) has masked entries
    if (j == jmax - 1) {
      int qbase = w * 16 + rg * 4;
#pragma unroll
      for (int ni = 0; ni < 4; ++ni) {
        int kcol = ni * 16 + cl;
#pragma unroll
        for (int r = 0; r < 4; ++r)
          if (kcol > qbase + r) sa[ni][r] = -1e30f;
      }
    }

    // online softmax (row lives in the 16 lanes sharing rg)
#pragma unroll
    for (int r = 0; r < 4; ++r) {
      float t = fmaxf(fmaxf(sa[0][r], sa[1][r]), fmaxf(sa[2][r], sa[3][r]));
      t = fmaxf(t, __shfl_xor(t, 1));
      t = fmaxf(t, __shfl_xor(t, 2));
      t = fmaxf(t, __shfl_xor(t, 4));
      t = fmaxf(t, __shfl_xor(t, 8));
      float mnew = fmaxf(mrow[r], t);
      float sf = __expf(mrow[r] - mnew);
      mrow[r] = mnew;
#pragma unroll
      for (int di = 0; di < 8; ++di) po[di][r] *= sf;
      float rs = 0.f;
#pragma unroll
      for (int ni = 0; ni < 4; ++ni) {
        float p = __expf(sa[ni][r] - mnew);
        sa[ni][r] = p;
        rs += p;
      }
      rs += __shfl_xor(rs, 1);
      rs += __shfl_xor(rs, 2);
      rs += __shfl_xor(rs, 4);
      rs += __shfl_xor(rs, 8);
      lrow[r] = lrow[r] * sf + rs;
    }

    // write P (wave-private 16-row slab; in-wave LDS ordering only)
#pragma unroll
    for (int ni = 0; ni < 4; ++ni)
#pragma unroll
      for (int r = 0; r < 4; ++r) {
        int prow = w * 16 + rg * 4 + r;
        int off = (prow * 128 + (ni * 16 + cl) * 2) ^ ((prow & 7) << 4);
        *(unsigned short*)((char*)Ps + off) = f2b(sa[ni][r]);
      }
    asm volatile("s_waitcnt lgkmcnt(0)" ::: "memory");
    __builtin_amdgcn_sched_barrier(0);

    // O += P V
    __builtin_amdgcn_s_setprio(1);
#pragma unroll
    for (int kk = 0; kk < 2; ++kk) {
      int prow = w * 16 + cl;
      int poff = (prow * 128 + (kk * 32 + rg * 8) * 2) ^ ((prow & 7) << 4);
      bf16x8 pa = *reinterpret_cast<const bf16x8*>((const char*)Ps + poff);
#pragma unroll
      for (int di = 0; di < 8; ++di) {
        int vrow = di * 16 + cl;
        int voff = (vrow * 128 + (kk * 32 + rg * 8) * 2) ^ ((vrow & 7) << 4);
        bf16x8 vb = *reinterpret_cast<const bf16x8*>((const char*)Vs + voff);
        po[di] = MFMA16(pa, vb, po[di]);
      }
    }
    __builtin_amdgcn_s_setprio(0);
  }

  // epilogue: normalize, write ctx[s][h*128+d]
#pragma unroll
  for (int r = 0; r < 4; ++r) {
    float inv = 1.0f / lrow[r];
    int srow = q0 + w * 16 + rg * 4 + r;
#pragma unroll
    for (int di = 0; di < 8; ++di)
      ctx[(size_t)srow * 4096 + h * 128 + di * 16 + cl] = f2b(po[di][r] * inv);
  }
}

// ---------- launch ----------
extern "C" void kernel_launch(void* const* d_in, const int* in_sizes, int n_in,
                              void* d_out, int out_size, void* d_ws, size_t ws_size,
                              hipStream_t stream) {
  const float* X    = (const float*)d_in[0];
  const float* cosb = (const float*)d_in[2];
  const float* sinb = (const float*)d_in[3];
  const float* Wq   = (const float*)d_in[4];
  const float* Wk   = (const float*)d_in[5];
  const float* Wv   = (const float*)d_in[6];
  const float* Wo   = (const float*)d_in[7];

  char* ws = (char*)d_ws;
  unsigned short* WT   = (unsigned short*)(ws + 0);           // 6144x4096 bf16 (later: WoT)
  unsigned short* Xb   = (unsigned short*)(ws + 50331648ull); // 2048x4096 bf16
  unsigned short* Cpre = (unsigned short*)(ws + 67108864ull); // 2048x6144 bf16 (later: ctx)
  unsigned short* Qr   = (unsigned short*)(ws + 92274688ull); // 32x2048x128 bf16
  unsigned short* Kr   = (unsigned short*)(ws + 109051904ull);// 8x2048x128 bf16
  unsigned short* Vt   = (unsigned short*)(ws + 113246208ull);// 8x128x2048 bf16
  unsigned short* ctx  = Cpre;

  k_transpose_f32_bf16<<<dim3(64, 64), 256, 0, stream>>>(Wq, WT, 4096, 4096);
  k_transpose_f32_bf16<<<dim3(64, 16), 256, 0, stream>>>(Wk, WT + (size_t)4096 * 4096, 4096, 1024);
  k_transpose_f32_bf16<<<dim3(64, 16), 256, 0, stream>>>(Wv, WT + (size_t)5120 * 4096, 4096, 1024);
  k_f32_to_bf16<<<8192, 256, 0, stream>>>(X, Xb);

  k_gemm<false><<<dim3(16, 48), 256, 0, stream>>>(Xb, WT, Cpre, 2048, 6144, 4096);

  k_rope<<<dim3(2048, 40), 128, 0, stream>>>(Cpre, cosb, sinb, Qr, Kr);
  k_transpose_v<<<dim3(32, 2, 8), 256, 0, stream>>>(Cpre, Vt);

  k_transpose_f32_bf16<<<dim3(64, 64), 256, 0, stream>>>(Wo, WT, 4096, 4096);

  k_attn<<<1024, 256, 0, stream>>>(Qr, Kr, Vt, ctx);

  k_gemm<true><<<dim3(16, 32), 256, 0, stream>>>(ctx, WT, d_out, 2048, 4096, 4096);
}